// Round 4
// baseline (183.920 us; speedup 1.0000x reference)
//
#include <hip/hip_runtime.h>

// Per-batch segment_sum with SORTED segment ids.
//   embeddings: (B=64, S=512, D=768) fp32; segment_ids: (B,S) int32 sorted.
//   out = concat(agg[:,0] (B,D), agg[:,1:] (B,S-1,D)) — flat B*S*D floats.
//
// R3 post-mortem: one wave per output row -> latency-bound (VALUBusy 4.9%,
// HBM 31%, ~1100 cyc/wave chain with ~8 KB useful traffic; id row re-read
// 512x per b = 64 MB extra L1 traffic).
// R4: one wave per G=4 CONSECUTIVE outputs of the same b.
//   - id row (2 KB) loaded once per wave, amortized 4x.
//   - all 5 run boundaries lb(g0..g0+4) computed up front via independent
//     cmp+ballot+popcll (popc -> scalar pipe; boundaries live in SGPRs ->
//     s_cmp-controlled uniform inner loops).
//   - the 4 runs concatenate into ONE contiguous row range: the wave streams
//     ~4 emb rows with affine addresses (prefetchable), writing each output
//     exactly once. No atomics, no zero pass, no extra dispatch.

constexpr int B  = 64;
constexpr int S  = 512;
constexpr int D  = 768;
constexpr int D4 = D / 4;          // 192 float4 per row = 64 lanes x 3
constexpr int G  = 4;              // outputs per wave
constexpr int BLOCK = 256;         // 4 waves per block

__global__ __launch_bounds__(BLOCK) void segsum_g4_kernel(
    const float4* __restrict__ emb,   // (B*S*D4)
    const int*    __restrict__ seg,   // (B*S)
    float4*       __restrict__ out) { // report (B*D4) then word (B*(S-1)*D4)
  const int wave = (blockIdx.x * BLOCK + threadIdx.x) >> 6;  // [0, B*S/G)
  const int lane = threadIdx.x & 63;
  const int b    = wave >> 7;              // wave / (S/G), S/G = 128
  const int g0   = (wave & 127) << 2;      // first of 4 consecutive segments

  // Whole id row: 2 coalesced int4 loads (L1-hot across the 128 waves of b).
  const int4* row = (const int4*)(seg + b * S);  // 128 int4
  const int4 a0 = row[lane];
  const int4 a1 = row[lane + 64];

  // bnd[k] = lower_bound(seg_row, g0+k) = #(x < g0+k), k = 0..G.
  // 40 independent v_cmp+ballot; popcll of the 64-bit mask -> s_bcnt (scalar).
  int bnd[G + 1];
#pragma unroll
  for (int k = 0; k <= G; ++k) {
    const int t = g0 + k;
    int c = 0;
    c += __popcll(__ballot(a0.x < t));
    c += __popcll(__ballot(a0.y < t));
    c += __popcll(__ballot(a0.z < t));
    c += __popcll(__ballot(a0.w < t));
    c += __popcll(__ballot(a1.x < t));
    c += __popcll(__ballot(a1.y < t));
    c += __popcll(__ballot(a1.z < t));
    c += __popcll(__ballot(a1.w < t));
    bnd[k] = c;
  }

  // Stream the concatenated runs [bnd[0], bnd[G]) — affine addresses.
  const float4* p = emb + (size_t)(b * S + bnd[0]) * D4 + lane;
#pragma unroll
  for (int k = 0; k < G; ++k) {
    float4 acc0 = make_float4(0.f, 0.f, 0.f, 0.f);
    float4 acc1 = acc0, acc2 = acc0;
    for (int s = bnd[k]; s < bnd[k + 1]; ++s) {   // SGPR trip count, uniform
      float4 e0 = p[0], e1 = p[64], e2 = p[128];
      acc0.x += e0.x; acc0.y += e0.y; acc0.z += e0.z; acc0.w += e0.w;
      acc1.x += e1.x; acc1.y += e1.y; acc1.z += e1.z; acc1.w += e1.w;
      acc2.x += e2.x; acc2.y += e2.y; acc2.z += e2.z; acc2.w += e2.w;
      p += D4;
    }
    const int g = g0 + k;
    float4* dst = (g == 0)
        ? out + (size_t)b * D4                                         // report
        : out + (size_t)B * D4 + ((size_t)b * (S - 1) + (g - 1)) * D4; // word
    dst[lane]       = acc0;
    dst[lane + 64]  = acc1;
    dst[lane + 128] = acc2;
  }
}

extern "C" void kernel_launch(void* const* d_in, const int* in_sizes, int n_in,
                              void* d_out, int out_size, void* d_ws, size_t ws_size,
                              hipStream_t stream) {
  const float4* emb = (const float4*)d_in[0];
  const int*    seg = (const int*)d_in[1];
  float4*       out = (float4*)d_out;

  const int waves  = B * S / G;                // 8192
  const int blocks = waves / (BLOCK / 64);     // 2048 blocks = 8 per CU
  segsum_g4_kernel<<<blocks, BLOCK, 0, stream>>>(emb, seg, out);
}

// Round 5
// 182.157 us; speedup vs baseline: 1.0097x; 1.0097x over previous
//
#include <hip/hip_runtime.h>

// Per-batch segment_sum with SORTED segment ids.
//   embeddings: (B=64, S=512, D=768) fp32; segment_ids: (B,S) int32 sorted.
//   out = concat(agg[:,0] (B,D), agg[:,1:] (B,S-1,D)) — flat B*S*D floats.
//
// R4 post-mortem: runtime-trip inner loop => global_load x3 -> s_waitcnt
// vmcnt(0) -> v_add per row = one serialized memory round trip per row;
// G=4 made 4 sequential round trips/wave while cutting TLP 4x -> 65 us at
// 2.3 TB/s (VALUBusy 3%: pure latency-bound).
// R5: same ballot boundaries, but
//   (1) level-0 rows of all 4 runs loaded as ONE batch of 12 independent
//       dwordx4 (accumulators initialized from them, no zero+add),
//   (2) only rare len>=2 remainders use the serial loop (~1.5 rounds/wave),
//   (3) empty runs write zeros with NO loads,
//   (4) nontemporal stores: 100 MB output is never re-read -> don't thrash
//       L2/L3, keep the input L3-resident.

typedef float v4f __attribute__((ext_vector_type(4)));

constexpr int B  = 64;
constexpr int S  = 512;
constexpr int D  = 768;
constexpr int D4 = D / 4;          // 192 float4 per row = 64 lanes x 3
constexpr int G  = 4;              // outputs per wave
constexpr int BLOCK = 256;         // 4 waves per block

__global__ __launch_bounds__(BLOCK) void segsum_r5_kernel(
    const v4f* __restrict__ emb,   // (B*S*D4)
    const int* __restrict__ seg,   // (B*S)
    v4f*       __restrict__ out) { // report (B*D4) then word (B*(S-1)*D4)
  const int wave = (blockIdx.x * BLOCK + threadIdx.x) >> 6;  // [0, B*S/G)
  const int lane = threadIdx.x & 63;
  const int b    = wave >> 7;              // wave / (S/G), S/G = 128
  const int g0   = (wave & 127) << 2;      // first of 4 consecutive segments

  // Whole id row: 2 coalesced int4 loads (L1/L2-hot across the 128 waves of b).
  const int4* row = (const int4*)(seg + b * S);  // 128 int4
  const int4 a0 = row[lane];
  const int4 a1 = row[lane + 64];

  // bnd[k] = #(x < g0+k) = lower_bound(seg_row, g0+k), k = 0..G.
  int bnd[G + 1];
#pragma unroll
  for (int k = 0; k <= G; ++k) {
    const int t = g0 + k;
    int c = 0;
    c += __popcll(__ballot(a0.x < t));
    c += __popcll(__ballot(a0.y < t));
    c += __popcll(__ballot(a0.z < t));
    c += __popcll(__ballot(a0.w < t));
    c += __popcll(__ballot(a1.x < t));
    c += __popcll(__ballot(a1.y < t));
    c += __popcll(__ballot(a1.z < t));
    c += __popcll(__ballot(a1.w < t));
    bnd[k] = c;
  }

  const v4f* base = emb + (size_t)b * S * D4 + lane;

  // (1) Level-0 batch: first row of every nonempty run, 12 independent loads
  // issued back-to-back (no waitcnt between them).
  v4f q[G][3];
#pragma unroll
  for (int k = 0; k < G; ++k) {
    if (bnd[k] < bnd[k + 1]) {             // wave-uniform (SGPR) branch
      const v4f* p = base + (size_t)bnd[k] * D4;
      q[k][0] = p[0];
      q[k][1] = p[64];
      q[k][2] = p[128];
    }
  }

  // (2)+(3)+(4) Finish each output and store it (earlier k can retire while
  // later k's loads are still in flight).
  const v4f zero = {0.f, 0.f, 0.f, 0.f};
#pragma unroll
  for (int k = 0; k < G; ++k) {
    if (bnd[k] >= bnd[k + 1]) {            // empty segment: zeros, no loads
      q[k][0] = zero; q[k][1] = zero; q[k][2] = zero;
    } else {
      for (int s = bnd[k] + 1; s < bnd[k + 1]; ++s) {  // rare (~26% of k)
        const v4f* p = base + (size_t)s * D4;
        v4f e0 = p[0], e1 = p[64], e2 = p[128];
        q[k][0] += e0; q[k][1] += e1; q[k][2] += e2;
      }
    }
    const int g = g0 + k;
    v4f* dst = (g == 0)
        ? out + (size_t)b * D4                                         // report
        : out + (size_t)B * D4 + ((size_t)b * (S - 1) + (g - 1)) * D4; // word
    __builtin_nontemporal_store(q[k][0], dst + lane);
    __builtin_nontemporal_store(q[k][1], dst + lane + 64);
    __builtin_nontemporal_store(q[k][2], dst + lane + 128);
  }
}

extern "C" void kernel_launch(void* const* d_in, const int* in_sizes, int n_in,
                              void* d_out, int out_size, void* d_ws, size_t ws_size,
                              hipStream_t stream) {
  const v4f* emb = (const v4f*)d_in[0];
  const int* seg = (const int*)d_in[1];
  v4f*       out = (v4f*)d_out;

  const int waves  = B * S / G;                // 8192
  const int blocks = waves / (BLOCK / 64);     // 2048 blocks = 8 per CU
  segsum_r5_kernel<<<blocks, BLOCK, 0, stream>>>(emb, seg, out);
}

// Round 6
// 179.345 us; speedup vs baseline: 1.0255x; 1.0157x over previous
//
#include <hip/hip_runtime.h>

// Per-batch segment_sum with SORTED segment ids.
//   embeddings: (B=64, S=512, D=768) fp32; segment_ids: (B,S) int32 sorted.
//   out = concat(agg[:,0] (B,D), agg[:,1:] (B,S-1,D)) — flat B*S*D floats.
//
// R5 post-mortem: compiler re-serialized the "batched" loads (VGPR=36 < the
// 48 needed), per-wave ILP is a dead end at source level. Cross-round
// effective-bytes accounting shows the winner axis is TLP + fewer redundant
// bytes: R3 (most waves) sustained 4.5 TB/s effective but wasted 64 MB on
// per-wave id re-reads.
// R6: R3-style TLP + LDS id sharing + G=2.
//   - 4096 blocks x 256 (16/CU, 2 generations for tail refill).
//   - block stages its b's 2-KB id row in LDS once (id traffic 64->8 MB);
//     waves ballot from LDS (independent cmp+popc, no dependent search).
//   - each wave: outputs g0 = 4*j+wave and g0+256 of the same b. Level-0
//     rows of both runs init the accumulators; rare len>=2 remainders loop;
//     empty segments store zeros with no loads.
//   - nontemporal stores: output is never re-read; keep L3 for the input.

typedef float v4f __attribute__((ext_vector_type(4)));

constexpr int B  = 64;
constexpr int S  = 512;
constexpr int D4 = 192;            // 768/4 float4 per row = 64 lanes x 3
constexpr int BLOCK = 256;         // 4 waves

__global__ __launch_bounds__(BLOCK) void segsum_r6_kernel(
    const v4f* __restrict__ emb,   // (B*S*D4)
    const int* __restrict__ seg,   // (B*S)
    v4f*       __restrict__ out) { // report (B*D4) then word (B*(S-1)*D4)
  __shared__ int4 sm[S / 4];       // 2 KB: one b-row of ids

  const int blk  = blockIdx.x;          // [0, B*64)
  const int b    = blk >> 6;
  const int j    = blk & 63;
  const int wv   = threadIdx.x >> 6;    // wave in block, 0..3
  const int lane = threadIdx.x & 63;

  if (threadIdx.x < S / 4)
    sm[threadIdx.x] = ((const int4*)(seg + b * S))[threadIdx.x];
  __syncthreads();

  const int4 a0 = sm[lane];
  const int4 a1 = sm[lane + 64];

  const int g0 = 4 * j + wv;            // [0,256)
  const int g1 = g0 + 256;              // [256,512)

  // lb(t) = #(id < t) via independent cmp+ballot+popc (scalar pipe).
  const int tg[4] = {g0, g0 + 1, g1, g1 + 1};
  int lb[4];
#pragma unroll
  for (int i = 0; i < 4; ++i) {
    const int t = tg[i];
    int c = 0;
    c += __popcll(__ballot(a0.x < t));
    c += __popcll(__ballot(a0.y < t));
    c += __popcll(__ballot(a0.z < t));
    c += __popcll(__ballot(a0.w < t));
    c += __popcll(__ballot(a1.x < t));
    c += __popcll(__ballot(a1.y < t));
    c += __popcll(__ballot(a1.z < t));
    c += __popcll(__ballot(a1.w < t));
    lb[i] = c;
  }

  const v4f* base = emb + (size_t)b * S * D4 + lane;
  const v4f zero = {0.f, 0.f, 0.f, 0.f};
  const bool ne0 = lb[0] < lb[1];       // wave-uniform
  const bool ne1 = lb[2] < lb[3];

  // Level-0 of both runs — 6 independent dwordx4.
  v4f q0a, q0b, q0c, q1a, q1b, q1c;
  if (ne0) { const v4f* p = base + (size_t)lb[0] * D4; q0a = p[0]; q0b = p[64]; q0c = p[128]; }
  if (ne1) { const v4f* p = base + (size_t)lb[2] * D4; q1a = p[0]; q1b = p[64]; q1c = p[128]; }

  // Output g0.
  if (!ne0) { q0a = zero; q0b = zero; q0c = zero; }
  else {
    for (int s = lb[0] + 1; s < lb[1]; ++s) {           // ~26% of outputs
      const v4f* p = base + (size_t)s * D4;
      q0a += p[0]; q0b += p[64]; q0c += p[128];
    }
  }
  {
    v4f* dst = (g0 == 0)
        ? out + (size_t)b * D4
        : out + (size_t)B * D4 + ((size_t)b * (S - 1) + (g0 - 1)) * D4;
    __builtin_nontemporal_store(q0a, dst + lane);
    __builtin_nontemporal_store(q0b, dst + lane + 64);
    __builtin_nontemporal_store(q0c, dst + lane + 128);
  }

  // Output g1 (never the report row).
  if (!ne1) { q1a = zero; q1b = zero; q1c = zero; }
  else {
    for (int s = lb[2] + 1; s < lb[3]; ++s) {
      const v4f* p = base + (size_t)s * D4;
      q1a += p[0]; q1b += p[64]; q1c += p[128];
    }
  }
  {
    v4f* dst = out + (size_t)B * D4 + ((size_t)b * (S - 1) + (g1 - 1)) * D4;
    __builtin_nontemporal_store(q1a, dst + lane);
    __builtin_nontemporal_store(q1b, dst + lane + 64);
    __builtin_nontemporal_store(q1c, dst + lane + 128);
  }
}

extern "C" void kernel_launch(void* const* d_in, const int* in_sizes, int n_in,
                              void* d_out, int out_size, void* d_ws, size_t ws_size,
                              hipStream_t stream) {
  const v4f* emb = (const v4f*)d_in[0];
  const int* seg = (const int*)d_in[1];
  v4f*       out = (v4f*)d_out;

  const int blocks = B * 64;                 // 4096 blocks = 16/CU
  segsum_r6_kernel<<<blocks, BLOCK, 0, stream>>>(emb, seg, out);
}